// Round 13
// baseline (352.122 us; speedup 1.0000x reference)
//
#include <hip/hip_runtime.h>
#include <math.h>

namespace {
constexpr int kB = 256;
constexpr int kD = 128;
constexpr int kN = 500000;
constexpr int kKC = 2049;             // K + 1
constexpr int kNPair = kB * kKC;      // 524544
constexpr float kTInv = 1.0f / 0.07f;
constexpr float kMom = 0.5f;
constexpr int kRB = 256;              // reduction grid size
constexpr long long kM = (long long)kN * kD;    // 64,000,000 floats per bank
constexpr long long kTot = 2 * kM;
constexpr int kChunk = 2048;                    // elems per scan block
constexpr int kNB1 = (kN + kChunk - 1) / kChunk; // 245
// fused10 geometry: 32-row tiles (exact: 500000/32 = 15625), 16 tiles/block
constexpr int kRows = 32;
constexpr int kTPB = kN / kRows;                 // 15625 tiles per bank (exact)
constexpr int kTiles = 2 * kTPB;                 // 31250
constexpr int kLdsStride = 132;                  // 528 B row pitch (16B-aligned)
constexpr int kTilesPerBlock = 16;
constexpr int kGrid10 = (kTiles + kTilesPerBlock - 1) / kTilesPerBlock; // 1954
}

// ---------- CSR setup: bucket pairs by row index ----------

__global__ __launch_bounds__(256) void hist_kernel(const int* __restrict__ cidx, int* __restrict__ A)
{
    int i = blockIdx.x * 256 + threadIdx.x;
    if (i < kNPair) atomicAdd(&A[cidx[i]], 1);
}

__global__ __launch_bounds__(256) void scan1_kernel(const int* __restrict__ A, int* __restrict__ bsum)
{
    long long base = (long long)blockIdx.x * kChunk;
    int t = threadIdx.x;
    int s = 0;
    #pragma unroll
    for (int j = 0; j < 8; ++j) {
        long long i = base + t * 8 + j;
        if (i < kN) s += A[i];
    }
    __shared__ int lds[256];
    lds[t] = s; __syncthreads();
    for (int st = 128; st > 0; st >>= 1) {
        if (t < st) lds[t] += lds[t + st];
        __syncthreads();
    }
    if (t == 0) bsum[blockIdx.x] = lds[0];
}

__global__ __launch_bounds__(256) void scan2_kernel(
    const int* __restrict__ bsum, int* __restrict__ bpre, int* __restrict__ offs)
{
    int t = threadIdx.x;
    int v = (t < kNB1) ? bsum[t] : 0;
    __shared__ int lds[256];
    lds[t] = v; __syncthreads();
    for (int st = 1; st < 256; st <<= 1) {
        int add = (t >= st) ? lds[t - st] : 0;
        __syncthreads();
        lds[t] += add;
        __syncthreads();
    }
    if (t < kNB1) bpre[t] = lds[t] - v;       // exclusive
    if (t == kNB1 - 1) offs[kN] = lds[t];     // total = kNPair
}

__global__ __launch_bounds__(256) void scan3_kernel(
    const int* __restrict__ A, const int* __restrict__ bpre, int* __restrict__ offs)
{
    int t = threadIdx.x;
    long long base = (long long)blockIdx.x * kChunk;
    int c[8]; int s = 0;
    #pragma unroll
    for (int j = 0; j < 8; ++j) {
        long long i = base + t * 8 + j;
        c[j] = (i < kN) ? A[i] : 0;
        s += c[j];
    }
    __shared__ int lds[256];
    lds[t] = s; __syncthreads();
    for (int st = 1; st < 256; st <<= 1) {
        int add = (t >= st) ? lds[t - st] : 0;
        __syncthreads();
        lds[t] += add;
        __syncthreads();
    }
    int excl = lds[t] - s + bpre[blockIdx.x];
    #pragma unroll
    for (int j = 0; j < 8; ++j) {
        long long i = base + t * 8 + j;
        if (i < kN) { offs[i] = excl; excl += c[j]; }
    }
}

// packs (row << 20) | pair so phase B needs ONE value per pair (no cidx chase)
__global__ __launch_bounds__(256) void scatter_kernel(
    const int* __restrict__ cidx, const int* __restrict__ offs,
    int* __restrict__ cur, long long* __restrict__ sorted64)
{
    int p = blockIdx.x * 256 + threadIdx.x;
    if (p < kNPair) {
        int r = cidx[p];
        int pos = offs[r] + atomicAdd(&cur[r], 1);
        sorted64[pos] = ((long long)r << 20) | (long long)p;
    }
}

// ---------- fused v10: fused9 + EARLY embed issue (B has zero global waits) --
// Per tile T: (1) prefetch T+1 stage regs + carry + sorted64 slice + offs(T+2);
// (2) EARLY: issue tile T's embed-row loads (pair list already in LDS from
//     T-1; one pair per 4-lane group, 8 float4/lane) — their L2 latency hides
//     under stage(T); (3) stage(T): regs -> LDS + shifted aligned out-stores;
// (4) raw s_barrier (lgkmcnt only; prefetch + emb stay in flight);
// (5) B(T): LDS rows x in-reg emb, 2-shuffle reduce, exp store. No global
//     dependency after the barrier -> high HBM duty cycle.
__global__ __launch_bounds__(256) void fused10_kernel(
    const float* __restrict__ mem1, const float* __restrict__ mem2,
    const float* __restrict__ teacher, const float* __restrict__ student,
    const int* __restrict__ offs, const long long* __restrict__ sorted64,
    float* __restrict__ out, float* __restrict__ e2, float* __restrict__ e1)
{
    __shared__ float tile[kRows * kLdsStride];   // 16896 B
    __shared__ long long s64lds[2][256];         // 4096 B
    const int tid = threadIdx.x;
    const int lane = tid & 63;
    const int w = tid >> 6;
    const int g = tid >> 2;        // 4-lane group id (0..63)
    const int sub = tid & 3;
    float4* ov = reinterpret_cast<float4*>(out);

    if (blockIdx.x == 0 && tid == 0) out[kTot] = mem2[kM - 1];  // final tail

    const int T0 = blockIdx.x * kTilesPerBlock;
    int T1 = T0 + kTilesPerBlock; if (T1 > kTiles) T1 = kTiles;
    const int nT = T1 - T0;

    auto r0of = [](int T) { return (T >= kTPB) ? (T - kTPB) * kRows : T * kRows; };

    // ---- prologue: offs(T0/T0+1), s64(T0) -> LDS, stage regs + carry (T0) ----
    int rA = r0of(T0);
    int oA = offs[rA];
    int cA = offs[rA + kRows] - oA;
    int TBn = (1 < nT) ? T0 + 1 : T0;
    int rB = r0of(TBn);
    int oB = offs[rB];
    int cB = (1 < nT) ? (offs[rB + kRows] - oB) : 0;
    {
        long long v = 0;
        if (tid < cA) v = sorted64[oA + tid];
        s64lds[0][tid] = v;
    }
    float4 sl0, sl1, sl2, sl3;
    float carry;
    {
        int bk = (T0 >= kTPB);
        const float4* bank4 = reinterpret_cast<const float4*>(bk ? mem2 : mem1);
        long long lb4 = (long long)(bk ? T0 - kTPB : T0) * (kRows * kD / 4) + w * 256;
        sl0 = bank4[lb4 + 0 * 64 + lane];
        sl1 = bank4[lb4 + 1 * 64 + lane];
        sl2 = bank4[lb4 + 2 * 64 + lane];
        sl3 = bank4[lb4 + 3 * 64 + lane];
        long long gb = (long long)bk * kM + (long long)rA * kD + (long long)w * 1024;
        carry = 0.f;
        if (gb > 0) { long long g2 = gb - 1; carry = (g2 < kM) ? mem1[g2] : mem2[g2 - kM]; }
    }
    __syncthreads();   // s64lds[0] visible to all

    for (int i = 0; i < nT; ++i) {
        const int T = T0 + i;
        const int cur = i & 1;
        const int bk = (T >= kTPB) ? 1 : 0;
        const int r0 = r0of(T);
        const int o0 = oA, cnt = cA;

        // ---- (1) prefetch stage regs + carry for T+1 ----
        float4 sn0, sn1, sn2, sn3;
        float carryn;
        {
            int Tn = (i + 1 < nT) ? T + 1 : T;
            int bkn = (Tn >= kTPB);
            const float4* bank4 = reinterpret_cast<const float4*>(bkn ? mem2 : mem1);
            long long lb4 = (long long)(bkn ? Tn - kTPB : Tn) * (kRows * kD / 4) + w * 256;
            sn0 = bank4[lb4 + 0 * 64 + lane];
            sn1 = bank4[lb4 + 1 * 64 + lane];
            sn2 = bank4[lb4 + 2 * 64 + lane];
            sn3 = bank4[lb4 + 3 * 64 + lane];
            long long gb = (long long)bkn * kM + (long long)r0of(Tn) * kD + (long long)w * 1024;
            carryn = 0.f;
            if (gb > 0) { long long g2 = gb - 1; carryn = (g2 < kM) ? mem1[g2] : mem2[g2 - kM]; }
        }
        // prefetch sorted64 slice for T+1
        long long s64n = 0;
        if (tid < cB) s64n = sorted64[oB + tid];
        // prefetch offs for T+2 (uniform -> scalar loads)
        int oC, cC;
        {
            int Tn2 = (i + 2 < nT) ? T + 2 : T;
            int rn2 = r0of(Tn2);
            oC = offs[rn2];
            cC = (i + 2 < nT) ? (offs[rn2 + kRows] - oC) : 0;
        }

        // ---- (2) EARLY embed issue for tile T (pair list already in LDS) ----
        const float4* emb4 = reinterpret_cast<const float4*>(bk ? student : teacher);
        long long vme = s64lds[cur][g];            // pair for this 4-lane group
        int pme = (int)(vme & 0xFFFFF);
        int lrme = (int)(vme >> 20) - r0;
        const float4* er = emb4
            + (long long)((unsigned)pme / (unsigned)kKC) * 32 + sub * 8;
        float4 ev0 = er[0], ev1 = er[1], ev2 = er[2], ev3 = er[3];
        float4 ev4 = er[4], ev5 = er[5], ev6 = er[6], ev7 = er[7];
        __builtin_amdgcn_sched_barrier(0);

        // ---- (3) stage(T): prefetched regs -> LDS + shifted out stores ----
        {
            const long long gbase = (long long)bk * kM + (long long)r0 * kD
                                    + (long long)w * 1024;
            const long long g4 = gbase >> 2;
            float cr = carry;
            float4 v[4] = {sl0, sl1, sl2, sl3};
            #pragma unroll
            for (int i2 = 0; i2 < 4; ++i2) {
                float4 c = v[i2];
                int lr = w * 8 + i2 * 2 + (lane >> 5);
                *reinterpret_cast<float4*>(&tile[lr * kLdsStride + (lane & 31) * 4]) = c;
                float pw = __shfl_up(c.w, 1);
                if (lane == 0) pw = cr;
                cr = __shfl(c.w, 63);
                long long k4 = g4 + i2 * 64 + lane;
                if (k4 != 0) {
                    ov[k4] = make_float4(pw, c.x, c.y, c.z);
                } else {
                    out[1] = c.x; out[2] = c.y; out[3] = c.z;
                }
            }
        }
        asm volatile("s_waitcnt lgkmcnt(0)" ::: "memory");
        __builtin_amdgcn_sched_barrier(0);
        __builtin_amdgcn_s_barrier();
        __builtin_amdgcn_sched_barrier(0);

        // ---- (5) B(T): LDS rows x in-reg emb; park next pair list ----
        {
            s64lds[cur ^ 1][tid] = s64n;

            float* ep = bk ? e1 : e2;   // bank1 -> e2 (teacher), bank2 -> e1
            if (g < cnt) {
                const float* row = &tile[lrme * kLdsStride + sub * 32];
                float4 r0v = *reinterpret_cast<const float4*>(&row[0]);
                float4 r1v = *reinterpret_cast<const float4*>(&row[4]);
                float4 r2v = *reinterpret_cast<const float4*>(&row[8]);
                float4 r3v = *reinterpret_cast<const float4*>(&row[12]);
                float4 r4v = *reinterpret_cast<const float4*>(&row[16]);
                float4 r5v = *reinterpret_cast<const float4*>(&row[20]);
                float4 r6v = *reinterpret_cast<const float4*>(&row[24]);
                float4 r7v = *reinterpret_cast<const float4*>(&row[28]);
                float ax = r0v.x*ev0.x + r0v.y*ev0.y + r0v.z*ev0.z + r0v.w*ev0.w;
                float ay = r1v.x*ev1.x + r1v.y*ev1.y + r1v.z*ev1.z + r1v.w*ev1.w;
                float az = r2v.x*ev2.x + r2v.y*ev2.y + r2v.z*ev2.z + r2v.w*ev2.w;
                float aw = r3v.x*ev3.x + r3v.y*ev3.y + r3v.z*ev3.z + r3v.w*ev3.w;
                ax += r4v.x*ev4.x + r4v.y*ev4.y + r4v.z*ev4.z + r4v.w*ev4.w;
                ay += r5v.x*ev5.x + r5v.y*ev5.y + r5v.z*ev5.z + r5v.w*ev5.w;
                az += r6v.x*ev6.x + r6v.y*ev6.y + r6v.z*ev6.z + r6v.w*ev6.w;
                aw += r7v.x*ev7.x + r7v.y*ev7.y + r7v.z*ev7.z + r7v.w*ev7.w;
                float d = (ax + ay) + (az + aw);
                d += __shfl_xor(d, 1);
                d += __shfl_xor(d, 2);
                if (sub == 0) ep[pme] = __expf(d * kTInv);
            }
            // remainder (cnt > 64): rare; latency exposed but negligible
            for (int t = 64 + g; t < cnt; t += 64) {
                long long v = (t < 256) ? s64lds[cur][t] : sorted64[o0 + t];
                int p  = (int)(v & 0xFFFFF);
                int lr = (int)(v >> 20) - r0;
                const float4* er2 = emb4
                    + (long long)((unsigned)p / (unsigned)kKC) * 32 + sub * 8;
                const float* row = &tile[lr * kLdsStride + sub * 32];
                float ax = 0.f, ay = 0.f, az = 0.f, aw = 0.f;
                #pragma unroll
                for (int kk = 0; kk < 8; ++kk) {
                    float4 evv = er2[kk];
                    float4 rvv = *reinterpret_cast<const float4*>(&row[kk * 4]);
                    ax += rvv.x * evv.x; ay += rvv.y * evv.y;
                    az += rvv.z * evv.z; aw += rvv.w * evv.w;
                }
                float d = (ax + ay) + (az + aw);
                d += __shfl_xor(d, 1);
                d += __shfl_xor(d, 2);
                if (sub == 0) ep[p] = __expf(d * kTInv);
            }
        }
        __builtin_amdgcn_sched_barrier(0);
        asm volatile("s_waitcnt lgkmcnt(0)" ::: "memory");
        __builtin_amdgcn_s_barrier();
        __builtin_amdgcn_sched_barrier(0);

        // ---- rotate pipeline state ----
        sl0 = sn0; sl1 = sn1; sl2 = sn2; sl3 = sn3;
        carry = carryn;
        oA = oB; cA = cB; oB = oC; cB = cC;
    }
}

// ---------- fallback path (R2): separate gather + copy ----------

__global__ __launch_bounds__(256) void dots_kernel(
    const float* __restrict__ mem1, const float* __restrict__ mem2,
    const float* __restrict__ teacher, const float* __restrict__ student,
    const int* __restrict__ cidx,
    float* __restrict__ e2, float* __restrict__ e1)
{
    int gtid = blockIdx.x * 256 + threadIdx.x;
    int wave = gtid >> 6;
    int lane = threadIdx.x & 63;
    if (wave >= kNPair) return;
    int b = wave / kKC;
    long long row = (long long)cidx[wave] * kD;
    const float2 m1 = *reinterpret_cast<const float2*>(mem1 + row + lane * 2);
    const float2 m2 = *reinterpret_cast<const float2*>(mem2 + row + lane * 2);
    const float2 tv = *reinterpret_cast<const float2*>(teacher + b * kD + lane * 2);
    const float2 sv = *reinterpret_cast<const float2*>(student + b * kD + lane * 2);
    float d1 = m1.x * tv.x + m1.y * tv.y;
    float d2 = m2.x * sv.x + m2.y * sv.y;
    #pragma unroll
    for (int off = 32; off > 0; off >>= 1) {
        d1 += __shfl_xor(d1, off);
        d2 += __shfl_xor(d2, off);
    }
    if (lane == 0) {
        e2[wave] = __expf(d1 * kTInv);
        e1[wave] = __expf(d2 * kTInv);
    }
}

__global__ __launch_bounds__(256) void copy_kernel(
    const float* __restrict__ mem1, const float* __restrict__ mem2,
    float* __restrict__ out)
{
    const long long NV4 = (kTot + 1) / 4;
    const long long KS  = kM / 4;
    const float4* m1v = reinterpret_cast<const float4*>(mem1);
    const float4* m2v = reinterpret_cast<const float4*>(mem2);
    float4* ov = reinterpret_cast<float4*>(out);
    long long stride = (long long)gridDim.x * 256;
    for (long long k = (long long)blockIdx.x * 256 + threadIdx.x; k < NV4; k += stride) {
        if (k == 0) {
            out[1] = mem1[0]; out[2] = mem1[1]; out[3] = mem1[2];
            out[kTot] = mem2[kM - 1];
            continue;
        }
        float4 r;
        if (k < KS) {
            float4 a = m1v[k - 1];
            float4 b = m1v[k];
            r = make_float4(a.w, b.x, b.y, b.z);
        } else if (k == KS) {
            r = make_float4(mem1[kM - 1], mem2[0], mem2[1], mem2[2]);
        } else {
            float4 a = m2v[k - KS - 1];
            float4 b = m2v[k - KS];
            r = make_float4(a.w, b.x, b.y, b.z);
        }
        ov[k] = r;
    }
}

// ---------- loss chain ----------

__global__ __launch_bounds__(256) void sums_kernel(
    const float* __restrict__ e2, const float* __restrict__ e1,
    float* __restrict__ p2, float* __restrict__ p1)
{
    __shared__ float s2[256], s1[256];
    float a2 = 0.f, a1 = 0.f;
    for (int i = blockIdx.x * 256 + threadIdx.x; i < kNPair; i += 256 * kRB) {
        a2 += e2[i];
        a1 += e1[i];
    }
    s2[threadIdx.x] = a2; s1[threadIdx.x] = a1;
    __syncthreads();
    for (int st = 128; st > 0; st >>= 1) {
        if ((int)threadIdx.x < st) {
            s2[threadIdx.x] += s2[threadIdx.x + st];
            s1[threadIdx.x] += s1[threadIdx.x + st];
        }
        __syncthreads();
    }
    if (threadIdx.x == 0) { p2[blockIdx.x] = s2[0]; p1[blockIdx.x] = s1[0]; }
}

// z merged in: each block reduces the 256 partials itself (deterministic).
__global__ __launch_bounds__(256) void lossp_kernel(
    const float* __restrict__ e2, const float* __restrict__ e1,
    const float* __restrict__ p2, const float* __restrict__ p1,
    float* __restrict__ lp)
{
    __shared__ float s2[256], s1[256];
    s2[threadIdx.x] = p2[threadIdx.x];
    s1[threadIdx.x] = p1[threadIdx.x];
    __syncthreads();
    for (int st = 128; st > 0; st >>= 1) {
        if ((int)threadIdx.x < st) {
            s2[threadIdx.x] += s2[threadIdx.x + st];
            s1[threadIdx.x] += s1[threadIdx.x + st];
        }
        __syncthreads();
    }
    const float scale = (float)kN / (float)kNPair;
    const float iz2 = 1.0f / (s2[0] * scale);
    const float iz1 = 1.0f / (s1[0] * scale);

    const float mpn = 2048.0f / 500000.0f;
    const float noise = mpn + 1e-7f;
    float acc = 0.f;
    for (int i = blockIdx.x * 256 + threadIdx.x; i < kNPair; i += 256 * kRB) {
        int k = i % kKC;
        float x2 = e2[i] * iz2;
        float x1 = e1[i] * iz1;
        if (k == 0) {
            acc += __logf(x2 / (x2 + noise)) + __logf(x1 / (x1 + noise));
        } else {
            acc += __logf(mpn / (x2 + noise)) + __logf(mpn / (x1 + noise));
        }
    }
    __syncthreads();
    __shared__ float s[256];
    s[threadIdx.x] = acc;
    __syncthreads();
    for (int st = 128; st > 0; st >>= 1) {
        if ((int)threadIdx.x < st) s[threadIdx.x] += s[threadIdx.x + st];
        __syncthreads();
    }
    if (threadIdx.x == 0) lp[blockIdx.x] = s[0];
}

__global__ __launch_bounds__(256) void final_kernel(
    const float* __restrict__ lp, float* __restrict__ out)
{
    __shared__ float s[256];
    s[threadIdx.x] = lp[threadIdx.x];
    __syncthreads();
    for (int st = 128; st > 0; st >>= 1) {
        if ((int)threadIdx.x < st) s[threadIdx.x] += s[threadIdx.x + st];
        __syncthreads();
    }
    if (threadIdx.x == 0) out[0] = -s[0] / (float)kB;
}

// ---------- momentum update of the 256 pos rows ----------

__global__ __launch_bounds__(64) void update_kernel(
    const float* __restrict__ mem1, const float* __restrict__ mem2,
    const float* __restrict__ student, const float* __restrict__ teacher,
    const int* __restrict__ pos_idx,
    float* __restrict__ out1, float* __restrict__ out2)
{
    int b = blockIdx.x;
    int lane = threadIdx.x;
    int p = pos_idx[b];
    for (int b2 = b + 1; b2 < kB; ++b2)
        if (pos_idx[b2] == p) return;   // a later write wins
    long long row = (long long)p * kD;
    float2 m1 = *reinterpret_cast<const float2*>(mem1 + row + lane * 2);
    float2 m2 = *reinterpret_cast<const float2*>(mem2 + row + lane * 2);
    float2 sv = *reinterpret_cast<const float2*>(student + b * kD + lane * 2);
    float2 tv = *reinterpret_cast<const float2*>(teacher + b * kD + lane * 2);
    float2 l1 = make_float2(m1.x * kMom + sv.x * (1.f - kMom),
                            m1.y * kMom + sv.y * (1.f - kMom));
    float2 l2 = make_float2(m2.x * kMom + tv.x * (1.f - kMom),
                            m2.y * kMom + tv.y * (1.f - kMom));
    float n1 = l1.x * l1.x + l1.y * l1.y;
    float n2 = l2.x * l2.x + l2.y * l2.y;
    #pragma unroll
    for (int off = 32; off > 0; off >>= 1) {
        n1 += __shfl_xor(n1, off);
        n2 += __shfl_xor(n2, off);
    }
    float i1 = 1.0f / sqrtf(n1);
    float i2 = 1.0f / sqrtf(n2);
    out1[row + lane * 2]     = l1.x * i1;
    out1[row + lane * 2 + 1] = l1.y * i1;
    out2[row + lane * 2]     = l2.x * i2;
    out2[row + lane * 2 + 1] = l2.y * i2;
}

extern "C" void kernel_launch(void* const* d_in, const int* in_sizes, int n_in,
                              void* d_out, int out_size, void* d_ws, size_t ws_size,
                              hipStream_t stream) {
    const float* student = (const float*)d_in[0];
    const float* teacher = (const float*)d_in[1];
    const float* mem1    = (const float*)d_in[2];
    const float* mem2    = (const float*)d_in[3];
    const int*   pos_idx = (const int*)d_in[4];
    const int*   cidx    = (const int*)d_in[5];

    float* out  = (float*)d_out;
    float* out1 = out + 1;
    float* out2 = out + 1 + kM;

    // ws layout (sorted64 right after e-arrays: 8B-aligned offset)
    float* ws = (float*)d_ws;
    float* e2 = ws;                            // kNPair
    float* e1 = e2 + kNPair;                   // kNPair
    long long* sorted64 = (long long*)(e1 + kNPair);   // kNPair (8B each)
    float* p2 = (float*)(sorted64 + kNPair);   // kRB
    float* p1 = p2 + kRB;                      // kRB
    float* lp = p1 + kRB;                      // kRB
    int*   A    = (int*)(lp + kRB);            // kN counts
    int*   cur  = A + kN;                      // kN scatter cursor
    int*   offs = cur + kN;                    // kN + 1
    int*   bsum = offs + kN + 1;               // kNB1
    int*   bpre = bsum + kNB1;                 // kNB1
    size_t need = (size_t)((char*)(bpre + kNB1) - (char*)d_ws);

    if (ws_size >= need) {
        // CSR setup (A and cur zeroed in one async memset)
        (void)hipMemsetAsync(A, 0, 2 * (size_t)kN * sizeof(int), stream);
        hist_kernel<<<(kNPair + 255) / 256, 256, 0, stream>>>(cidx, A);
        scan1_kernel<<<kNB1, 256, 0, stream>>>(A, bsum);
        scan2_kernel<<<1, 256, 0, stream>>>(bsum, bpre, offs);
        scan3_kernel<<<kNB1, 256, 0, stream>>>(A, bpre, offs);
        scatter_kernel<<<(kNPair + 255) / 256, 256, 0, stream>>>(cidx, offs, cur, sorted64);
        // fused tiled copy + dots, early-emb pipeline
        fused10_kernel<<<kGrid10, 256, 0, stream>>>(mem1, mem2, teacher, student,
                                                    offs, sorted64, out, e2, e1);
    } else {
        // fallback: R2 path
        int nblocks = (kNPair + 3) / 4;
        dots_kernel<<<nblocks, 256, 0, stream>>>(mem1, mem2, teacher, student, cidx, e2, e1);
        copy_kernel<<<2048, 256, 0, stream>>>(mem1, mem2, out);
    }

    sums_kernel<<<kRB, 256, 0, stream>>>(e2, e1, p2, p1);
    lossp_kernel<<<kRB, 256, 0, stream>>>(e2, e1, p2, p1, lp);
    final_kernel<<<1, 256, 0, stream>>>(lp, out);
    update_kernel<<<kB, 64, 0, stream>>>(mem1, mem2, student, teacher, pos_idx, out1, out2);
}

// Round 14
// 334.538 us; speedup vs baseline: 1.0526x; 1.0526x over previous
//
#include <hip/hip_runtime.h>
#include <math.h>

namespace {
constexpr int kB = 256;
constexpr int kD = 128;
constexpr int kN = 500000;
constexpr int kKC = 2049;             // K + 1
constexpr int kNPair = kB * kKC;      // 524544
constexpr float kTInv = 1.0f / 0.07f;
constexpr float kMom = 0.5f;
constexpr int kRB = 256;              // reduction grid size
constexpr long long kM = (long long)kN * kD;    // 64,000,000 floats per bank
constexpr long long kTot = 2 * kM;              // 128,000,000
// mixed2 geometry: 2048 blocks; first 256 = dots role, rest = copy role
constexpr int kBlocks = 2048;
constexpr int kDotsBlocks = 256;
constexpr int kCopyBlocks = kBlocks - kDotsBlocks;          // 1792
constexpr long long kWL = 500000;     // total wave-loads (64 float4 each)
constexpr long long kWLB = 250000;    // wave-loads in bank 1 (boundary-aligned)
constexpr int kCopyWaves = kCopyBlocks * 4;                 // 7168
constexpr int kWLperWave = (int)((kWL + kCopyWaves - 1) / kCopyWaves); // 70
constexpr int kStreams = kDotsBlocks * 4 * 16 / 2;          // 8192 pair-streams/side
}

// ---------- mixed v2: copy role streams at HBM BW; dots role rides its
// L2/L3 wake (R7 evidence: gather reads almost fully cache-absorbed).
// Copy: contiguous carry-walk per wave — 1 aligned float4 load + 1 aligned
// float4 store per 16B (no duplicate loads, no branchy index math), 1-ahead
// prefetch; ~70 wave-loads per wave.
// Dots: one (pair,side) per 4-lane group — 16 independent float4 loads/lane
// (8 row + 8 emb), 32 FMAs, 2 shuffles, exp store. cidx prefetched one
// iteration ahead. No CSR, no LDS, no barriers.
__global__ __launch_bounds__(256) void mixed2_kernel(
    const float* __restrict__ mem1, const float* __restrict__ mem2,
    const float* __restrict__ teacher, const float* __restrict__ student,
    const int* __restrict__ cidx,
    float* __restrict__ out, float* __restrict__ e2, float* __restrict__ e1)
{
    const int tid = threadIdx.x;
    const int lane = tid & 63;
    const float4* m1v = reinterpret_cast<const float4*>(mem1);
    const float4* m2v = reinterpret_cast<const float4*>(mem2);

    if ((int)blockIdx.x >= kDotsBlocks) {
        // ================= copy role =================
        float4* ov = reinterpret_cast<float4*>(out);
        long long wv = (long long)(blockIdx.x - kDotsBlocks) * 4 + (tid >> 6);
        long long j0 = wv * kWLperWave;
        if (j0 >= kWL) return;
        long long j1 = j0 + kWLperWave; if (j1 > kWL) j1 = kWL;
        if (wv == 0 && lane == 0) out[kTot] = mem2[kM - 1];   // final tail

        float carry = 0.f;
        if (j0 > 0) {
            long long g = j0 * 256 - 1;
            carry = (g < kM) ? mem1[g] : mem2[g - kM];
        }
        float4 cur = (j0 < kWLB) ? m1v[j0 * 64 + lane]
                                 : m2v[(j0 - kWLB) * 64 + lane];
        for (long long j = j0; j < j1; ++j) {
            float4 nxt = make_float4(0.f, 0.f, 0.f, 0.f);
            long long jn = j + 1;
            if (jn < j1)
                nxt = (jn < kWLB) ? m1v[jn * 64 + lane]
                                  : m2v[(jn - kWLB) * 64 + lane];
            float pw = __shfl_up(cur.w, 1);
            if (lane == 0) pw = carry;
            carry = __shfl(cur.w, 63);
            long long k = j * 64 + lane;
            if (k != 0) {
                ov[k] = make_float4(pw, cur.x, cur.y, cur.z);
            } else {
                out[1] = cur.x; out[2] = cur.y; out[3] = cur.z;
            }
            cur = nxt;
        }
    } else {
        // ================= dots role =================
        const int sub = lane & 3;
        const int gid = ((int)blockIdx.x * 4 + (tid >> 6)) * 16 + (lane >> 2);
        const int side = gid & 1;          // 0: mem1·teacher->e2, 1: mem2·student->e1
        const int p0 = gid >> 1;           // 0..8191
        const float4* bank4 = side ? m2v : m1v;
        const float4* emb4  = reinterpret_cast<const float4*>(side ? student : teacher);
        float* ep = side ? e1 : e2;

        int rn = cidx[p0];
        for (int p = p0; p < kNPair; p += kStreams) {
            int r = rn;
            int pn = p + kStreams;
            if (pn < kNPair) rn = cidx[pn];    // prefetch next row index

            const float4* rw = bank4 + (long long)r * 32 + sub * 8;
            const float4* er = emb4
                + (long long)((unsigned)p / (unsigned)kKC) * 32 + sub * 8;
            float4 r0 = rw[0], r1 = rw[1], r2 = rw[2], r3 = rw[3];
            float4 r4 = rw[4], r5 = rw[5], r6 = rw[6], r7 = rw[7];
            float4 b0 = er[0], b1 = er[1], b2 = er[2], b3 = er[3];
            float4 b4 = er[4], b5 = er[5], b6 = er[6], b7 = er[7];
            float ax = r0.x*b0.x + r0.y*b0.y + r0.z*b0.z + r0.w*b0.w;
            float ay = r1.x*b1.x + r1.y*b1.y + r1.z*b1.z + r1.w*b1.w;
            float az = r2.x*b2.x + r2.y*b2.y + r2.z*b2.z + r2.w*b2.w;
            float aw = r3.x*b3.x + r3.y*b3.y + r3.z*b3.z + r3.w*b3.w;
            ax += r4.x*b4.x + r4.y*b4.y + r4.z*b4.z + r4.w*b4.w;
            ay += r5.x*b5.x + r5.y*b5.y + r5.z*b5.z + r5.w*b5.w;
            az += r6.x*b6.x + r6.y*b6.y + r6.z*b6.z + r6.w*b6.w;
            aw += r7.x*b7.x + r7.y*b7.y + r7.z*b7.z + r7.w*b7.w;
            float d = (ax + ay) + (az + aw);
            d += __shfl_xor(d, 1);
            d += __shfl_xor(d, 2);
            if (sub == 0) ep[p] = __expf(d * kTInv);
        }
    }
}

// ---------- loss chain ----------

__global__ __launch_bounds__(256) void sums_kernel(
    const float* __restrict__ e2, const float* __restrict__ e1,
    float* __restrict__ p2, float* __restrict__ p1)
{
    __shared__ float s2[256], s1[256];
    float a2 = 0.f, a1 = 0.f;
    for (int i = blockIdx.x * 256 + threadIdx.x; i < kNPair; i += 256 * kRB) {
        a2 += e2[i];
        a1 += e1[i];
    }
    s2[threadIdx.x] = a2; s1[threadIdx.x] = a1;
    __syncthreads();
    for (int st = 128; st > 0; st >>= 1) {
        if ((int)threadIdx.x < st) {
            s2[threadIdx.x] += s2[threadIdx.x + st];
            s1[threadIdx.x] += s1[threadIdx.x + st];
        }
        __syncthreads();
    }
    if (threadIdx.x == 0) { p2[blockIdx.x] = s2[0]; p1[blockIdx.x] = s1[0]; }
}

// z merged in: each block reduces the 256 partials itself (deterministic).
__global__ __launch_bounds__(256) void lossp_kernel(
    const float* __restrict__ e2, const float* __restrict__ e1,
    const float* __restrict__ p2, const float* __restrict__ p1,
    float* __restrict__ lp)
{
    __shared__ float s2[256], s1[256];
    s2[threadIdx.x] = p2[threadIdx.x];
    s1[threadIdx.x] = p1[threadIdx.x];
    __syncthreads();
    for (int st = 128; st > 0; st >>= 1) {
        if ((int)threadIdx.x < st) {
            s2[threadIdx.x] += s2[threadIdx.x + st];
            s1[threadIdx.x] += s1[threadIdx.x + st];
        }
        __syncthreads();
    }
    const float scale = (float)kN / (float)kNPair;
    const float iz2 = 1.0f / (s2[0] * scale);
    const float iz1 = 1.0f / (s1[0] * scale);

    const float mpn = 2048.0f / 500000.0f;
    const float noise = mpn + 1e-7f;
    float acc = 0.f;
    for (int i = blockIdx.x * 256 + threadIdx.x; i < kNPair; i += 256 * kRB) {
        int k = i % kKC;
        float x2 = e2[i] * iz2;
        float x1 = e1[i] * iz1;
        if (k == 0) {
            acc += __logf(x2 / (x2 + noise)) + __logf(x1 / (x1 + noise));
        } else {
            acc += __logf(mpn / (x2 + noise)) + __logf(mpn / (x1 + noise));
        }
    }
    __syncthreads();
    __shared__ float s[256];
    s[threadIdx.x] = acc;
    __syncthreads();
    for (int st = 128; st > 0; st >>= 1) {
        if ((int)threadIdx.x < st) s[threadIdx.x] += s[threadIdx.x + st];
        __syncthreads();
    }
    if (threadIdx.x == 0) lp[blockIdx.x] = s[0];
}

__global__ __launch_bounds__(256) void final_kernel(
    const float* __restrict__ lp, float* __restrict__ out)
{
    __shared__ float s[256];
    s[threadIdx.x] = lp[threadIdx.x];
    __syncthreads();
    for (int st = 128; st > 0; st >>= 1) {
        if ((int)threadIdx.x < st) s[threadIdx.x] += s[threadIdx.x + st];
        __syncthreads();
    }
    if (threadIdx.x == 0) out[0] = -s[0] / (float)kB;
}

// ---------- momentum update of the 256 pos rows ----------

__global__ __launch_bounds__(64) void update_kernel(
    const float* __restrict__ mem1, const float* __restrict__ mem2,
    const float* __restrict__ student, const float* __restrict__ teacher,
    const int* __restrict__ pos_idx,
    float* __restrict__ out1, float* __restrict__ out2)
{
    int b = blockIdx.x;
    int lane = threadIdx.x;
    int p = pos_idx[b];
    for (int b2 = b + 1; b2 < kB; ++b2)
        if (pos_idx[b2] == p) return;   // a later write wins
    long long row = (long long)p * kD;
    float2 m1 = *reinterpret_cast<const float2*>(mem1 + row + lane * 2);
    float2 m2 = *reinterpret_cast<const float2*>(mem2 + row + lane * 2);
    float2 sv = *reinterpret_cast<const float2*>(student + b * kD + lane * 2);
    float2 tv = *reinterpret_cast<const float2*>(teacher + b * kD + lane * 2);
    // v1 pairs with student, v2 pairs with teacher (per reference)
    float2 l1 = make_float2(m1.x * kMom + sv.x * (1.f - kMom),
                            m1.y * kMom + sv.y * (1.f - kMom));
    float2 l2 = make_float2(m2.x * kMom + tv.x * (1.f - kMom),
                            m2.y * kMom + tv.y * (1.f - kMom));
    float n1 = l1.x * l1.x + l1.y * l1.y;
    float n2 = l2.x * l2.x + l2.y * l2.y;
    #pragma unroll
    for (int off = 32; off > 0; off >>= 1) {
        n1 += __shfl_xor(n1, off);
        n2 += __shfl_xor(n2, off);
    }
    float i1 = 1.0f / sqrtf(n1);
    float i2 = 1.0f / sqrtf(n2);
    out1[row + lane * 2]     = l1.x * i1;
    out1[row + lane * 2 + 1] = l1.y * i1;
    out2[row + lane * 2]     = l2.x * i2;
    out2[row + lane * 2 + 1] = l2.y * i2;
}

extern "C" void kernel_launch(void* const* d_in, const int* in_sizes, int n_in,
                              void* d_out, int out_size, void* d_ws, size_t ws_size,
                              hipStream_t stream) {
    const float* student = (const float*)d_in[0];
    const float* teacher = (const float*)d_in[1];
    const float* mem1    = (const float*)d_in[2];
    const float* mem2    = (const float*)d_in[3];
    const int*   pos_idx = (const int*)d_in[4];
    const int*   cidx    = (const int*)d_in[5];

    float* out  = (float*)d_out;
    float* out1 = out + 1;                // new_memory_v1
    float* out2 = out + 1 + kM;           // new_memory_v2

    float* ws = (float*)d_ws;
    float* e2 = ws;                       // kNPair exps (mem1 . teacher)
    float* e1 = e2 + kNPair;              // kNPair exps (mem2 . student)
    float* p2 = e1 + kNPair;              // kRB
    float* p1 = p2 + kRB;                 // kRB
    float* lp = p1 + kRB;                 // kRB

    mixed2_kernel<<<kBlocks, 256, 0, stream>>>(mem1, mem2, teacher, student,
                                               cidx, out, e2, e1);
    sums_kernel<<<kRB, 256, 0, stream>>>(e2, e1, p2, p1);
    lossp_kernel<<<kRB, 256, 0, stream>>>(e2, e1, p2, p1, lp);
    final_kernel<<<1, 256, 0, stream>>>(lp, out);
    update_kernel<<<kB, 64, 0, stream>>>(mem1, mem2, student, teacher, pos_idx, out1, out2);
}

// Round 16
// 309.145 us; speedup vs baseline: 1.1390x; 1.0821x over previous
//
#include <hip/hip_runtime.h>
#include <math.h>

namespace {
constexpr int kB = 256;
constexpr int kD = 128;
constexpr int kN = 500000;
constexpr int kKC = 2049;             // K + 1
constexpr int kNPair = kB * kKC;      // 524544
constexpr float kTInv = 1.0f / 0.07f;
constexpr float kMom = 0.5f;
constexpr int kRB = 256;              // reduction grid size
constexpr long long kM = (long long)kN * kD;    // 64,000,000 floats per bank
constexpr long long kTot = 2 * kM;
constexpr int kChunk = 2048;                    // elems per scan block
constexpr int kNB1 = (kN + kChunk - 1) / kChunk; // 245
// fused9 geometry: 32-row tiles (exact: 500000/32 = 15625), 16 tiles/block
constexpr int kRows = 32;
constexpr int kTPB = kN / kRows;                 // 15625 tiles per bank (exact)
constexpr int kTiles = 2 * kTPB;                 // 31250
constexpr int kLdsStride = 132;                  // 528 B row pitch (16B-aligned)
constexpr int kTilesPerBlock = 16;
constexpr int kGrid9 = (kTiles + kTilesPerBlock - 1) / kTilesPerBlock; // 1954

typedef float fx4 __attribute__((ext_vector_type(4)));   // NT-store-legal vec4
}

// ---------- CSR setup: bucket pairs by row index ----------

__global__ __launch_bounds__(256) void hist_kernel(const int* __restrict__ cidx, int* __restrict__ A)
{
    int i = blockIdx.x * 256 + threadIdx.x;
    if (i < kNPair) atomicAdd(&A[cidx[i]], 1);
}

__global__ __launch_bounds__(256) void scan1_kernel(const int* __restrict__ A, int* __restrict__ bsum)
{
    long long base = (long long)blockIdx.x * kChunk;
    int t = threadIdx.x;
    int s = 0;
    #pragma unroll
    for (int j = 0; j < 8; ++j) {
        long long i = base + t * 8 + j;
        if (i < kN) s += A[i];
    }
    __shared__ int lds[256];
    lds[t] = s; __syncthreads();
    for (int st = 128; st > 0; st >>= 1) {
        if (t < st) lds[t] += lds[t + st];
        __syncthreads();
    }
    if (t == 0) bsum[blockIdx.x] = lds[0];
}

__global__ __launch_bounds__(256) void scan2_kernel(
    const int* __restrict__ bsum, int* __restrict__ bpre, int* __restrict__ offs)
{
    int t = threadIdx.x;
    int v = (t < kNB1) ? bsum[t] : 0;
    __shared__ int lds[256];
    lds[t] = v; __syncthreads();
    for (int st = 1; st < 256; st <<= 1) {
        int add = (t >= st) ? lds[t - st] : 0;
        __syncthreads();
        lds[t] += add;
        __syncthreads();
    }
    if (t < kNB1) bpre[t] = lds[t] - v;       // exclusive
    if (t == kNB1 - 1) offs[kN] = lds[t];     // total = kNPair
}

__global__ __launch_bounds__(256) void scan3_kernel(
    const int* __restrict__ A, const int* __restrict__ bpre, int* __restrict__ offs)
{
    int t = threadIdx.x;
    long long base = (long long)blockIdx.x * kChunk;
    int c[8]; int s = 0;
    #pragma unroll
    for (int j = 0; j < 8; ++j) {
        long long i = base + t * 8 + j;
        c[j] = (i < kN) ? A[i] : 0;
        s += c[j];
    }
    __shared__ int lds[256];
    lds[t] = s; __syncthreads();
    for (int st = 1; st < 256; st <<= 1) {
        int add = (t >= st) ? lds[t - st] : 0;
        __syncthreads();
        lds[t] += add;
        __syncthreads();
    }
    int excl = lds[t] - s + bpre[blockIdx.x];
    #pragma unroll
    for (int j = 0; j < 8; ++j) {
        long long i = base + t * 8 + j;
        if (i < kN) { offs[i] = excl; excl += c[j]; }
    }
}

// packs (row << 20) | pair so phase B needs ONE value per pair (no cidx chase)
__global__ __launch_bounds__(256) void scatter_kernel(
    const int* __restrict__ cidx, const int* __restrict__ offs,
    int* __restrict__ cur, long long* __restrict__ sorted64)
{
    int p = blockIdx.x * 256 + threadIdx.x;
    if (p < kNPair) {
        int r = cidx[p];
        int pos = offs[r] + atomicAdd(&cur[r], 1);
        sorted64[pos] = ((long long)r << 20) | (long long)p;
    }
}

// ---------- fused v9nt: fused9 + non-temporal output stores ----------
// Identical schedule to fused9 (best, 323 total). Only change: the output
// stream stores use __builtin_nontemporal_store (nt flag) so the 1GB
// write-once stream doesn't evict source-bank lines from L2/L3 — raising
// the read hit rate (gather + replay-to-replay retention).
__global__ __launch_bounds__(256) void fused9_kernel(
    const float* __restrict__ mem1, const float* __restrict__ mem2,
    const float* __restrict__ teacher, const float* __restrict__ student,
    const int* __restrict__ offs, const long long* __restrict__ sorted64,
    float* __restrict__ out, float* __restrict__ e2, float* __restrict__ e1)
{
    __shared__ float tile[kRows * kLdsStride];   // 16896 B
    __shared__ long long s64lds[2][256];         // 4096 B
    const int tid = threadIdx.x;
    const int lane = tid & 63;
    const int w = tid >> 6;
    fx4* ov = reinterpret_cast<fx4*>(out);

    if (blockIdx.x == 0 && tid == 0)
        __builtin_nontemporal_store(mem2[kM - 1], &out[kTot]);  // final tail

    const int T0 = blockIdx.x * kTilesPerBlock;
    int T1 = T0 + kTilesPerBlock; if (T1 > kTiles) T1 = kTiles;
    const int nT = T1 - T0;

    auto r0of = [](int T) { return (T >= kTPB) ? (T - kTPB) * kRows : T * kRows; };

    // ---- prologue: offs(T0/T0+1), s64(T0), stage regs + carry (T0) ----
    int rA = r0of(T0);
    int oA = offs[rA];
    int cA = offs[rA + kRows] - oA;
    int TBn = (1 < nT) ? T0 + 1 : T0;
    int rB = r0of(TBn);
    int oB = offs[rB];
    int cB = (1 < nT) ? (offs[rB + kRows] - oB) : 0;
    {
        long long v = 0;
        if (tid < cA) v = sorted64[oA + tid];
        s64lds[0][tid] = v;
    }
    float4 sl0, sl1, sl2, sl3;
    float carry;
    {
        int bk = (T0 >= kTPB);
        const float4* bank4 = reinterpret_cast<const float4*>(bk ? mem2 : mem1);
        long long lb4 = (long long)(bk ? T0 - kTPB : T0) * (kRows * kD / 4) + w * 256;
        sl0 = bank4[lb4 + 0 * 64 + lane];
        sl1 = bank4[lb4 + 1 * 64 + lane];
        sl2 = bank4[lb4 + 2 * 64 + lane];
        sl3 = bank4[lb4 + 3 * 64 + lane];
        long long gb = (long long)bk * kM + (long long)rA * kD + (long long)w * 1024;
        carry = 0.f;
        if (gb > 0) { long long g2 = gb - 1; carry = (g2 < kM) ? mem1[g2] : mem2[g2 - kM]; }
    }

    for (int i = 0; i < nT; ++i) {
        const int T = T0 + i;
        const int cur = i & 1;
        const int bk = (T >= kTPB) ? 1 : 0;
        const int r0 = r0of(T);
        const int o0 = oA, cnt = cA;

        // ---- prefetch stage regs + carry for T+1 ----
        float4 sn0, sn1, sn2, sn3;
        float carryn;
        {
            int Tn = (i + 1 < nT) ? T + 1 : T;
            int bkn = (Tn >= kTPB);
            const float4* bank4 = reinterpret_cast<const float4*>(bkn ? mem2 : mem1);
            long long lb4 = (long long)(bkn ? Tn - kTPB : Tn) * (kRows * kD / 4) + w * 256;
            sn0 = bank4[lb4 + 0 * 64 + lane];
            sn1 = bank4[lb4 + 1 * 64 + lane];
            sn2 = bank4[lb4 + 2 * 64 + lane];
            sn3 = bank4[lb4 + 3 * 64 + lane];
            long long gb = (long long)bkn * kM + (long long)r0of(Tn) * kD + (long long)w * 1024;
            carryn = 0.f;
            if (gb > 0) { long long g2 = gb - 1; carryn = (g2 < kM) ? mem1[g2] : mem2[g2 - kM]; }
        }
        // prefetch sorted64 slice for T+1
        long long s64n = 0;
        if (tid < cB) s64n = sorted64[oB + tid];
        // prefetch offs for T+2 (uniform -> scalar loads)
        int oC, cC;
        {
            int Tn2 = (i + 2 < nT) ? T + 2 : T;
            int rn2 = r0of(Tn2);
            oC = offs[rn2];
            cC = (i + 2 < nT) ? (offs[rn2 + kRows] - oC) : 0;
        }
        __builtin_amdgcn_sched_barrier(0);

        // ---- stage(T): prefetched regs -> LDS + shifted NT out stores ----
        {
            const long long gbase = (long long)bk * kM + (long long)r0 * kD
                                    + (long long)w * 1024;
            const long long g4 = gbase >> 2;
            float cr = carry;
            float4 v[4] = {sl0, sl1, sl2, sl3};
            #pragma unroll
            for (int i2 = 0; i2 < 4; ++i2) {
                float4 c = v[i2];
                int lr = w * 8 + i2 * 2 + (lane >> 5);
                *reinterpret_cast<float4*>(&tile[lr * kLdsStride + (lane & 31) * 4]) = c;
                float pw = __shfl_up(c.w, 1);
                if (lane == 0) pw = cr;
                cr = __shfl(c.w, 63);
                long long k4 = g4 + i2 * 64 + lane;
                if (k4 != 0) {
                    fx4 st = {pw, c.x, c.y, c.z};
                    __builtin_nontemporal_store(st, &ov[k4]);
                } else {
                    __builtin_nontemporal_store(c.x, &out[1]);
                    __builtin_nontemporal_store(c.y, &out[2]);
                    __builtin_nontemporal_store(c.z, &out[3]);
                }
            }
        }
        asm volatile("s_waitcnt lgkmcnt(0)" ::: "memory");
        __builtin_amdgcn_sched_barrier(0);
        __builtin_amdgcn_s_barrier();
        __builtin_amdgcn_sched_barrier(0);

        // ---- B(T): pair dots; 4-lane cooperative emb load (one L2 trip) ----
        {
            // park next tile's pair list in the other LDS buffer
            s64lds[cur ^ 1][tid] = s64n;

            const float4* emb4 = reinterpret_cast<const float4*>(bk ? student : teacher);
            float* ep = bk ? e1 : e2;   // bank1 -> e2 (teacher), bank2 -> e1
            const int sub = tid & 3;
            for (int t = tid >> 2; t < cnt; t += 64) {
                long long v = (t < 256) ? s64lds[cur][t] : sorted64[o0 + t];
                int p  = (int)(v & 0xFFFFF);
                int lr = (int)(v >> 20) - r0;
                const float4* er = emb4
                    + (long long)((unsigned)p / (unsigned)kKC) * 32 + sub * 8;
                const float* row = &tile[lr * kLdsStride + sub * 32];
                float ax = 0.f, ay = 0.f, az = 0.f, aw = 0.f;
                #pragma unroll
                for (int kk = 0; kk < 8; ++kk) {
                    int c4 = (kk + sub * 2) & 7;     // bank-rotated chunk order
                    float4 ev = er[c4];
                    float4 rv = *reinterpret_cast<const float4*>(&row[c4 * 4]);
                    ax += rv.x * ev.x; ay += rv.y * ev.y;
                    az += rv.z * ev.z; aw += rv.w * ev.w;
                }
                float d = (ax + ay) + (az + aw);
                d += __shfl_xor(d, 1);
                d += __shfl_xor(d, 2);
                if (sub == 0) ep[p] = __expf(d * kTInv);
            }
        }
        __builtin_amdgcn_sched_barrier(0);
        asm volatile("s_waitcnt lgkmcnt(0)" ::: "memory");
        __builtin_amdgcn_s_barrier();
        __builtin_amdgcn_sched_barrier(0);

        // ---- rotate pipeline state ----
        sl0 = sn0; sl1 = sn1; sl2 = sn2; sl3 = sn3;
        carry = carryn;
        oA = oB; cA = cB; oB = oC; cB = cC;
    }
}

// ---------- fallback path (R2): separate gather + copy ----------

__global__ __launch_bounds__(256) void dots_kernel(
    const float* __restrict__ mem1, const float* __restrict__ mem2,
    const float* __restrict__ teacher, const float* __restrict__ student,
    const int* __restrict__ cidx,
    float* __restrict__ e2, float* __restrict__ e1)
{
    int gtid = blockIdx.x * 256 + threadIdx.x;
    int wave = gtid >> 6;
    int lane = threadIdx.x & 63;
    if (wave >= kNPair) return;
    int b = wave / kKC;
    long long row = (long long)cidx[wave] * kD;
    const float2 m1 = *reinterpret_cast<const float2*>(mem1 + row + lane * 2);
    const float2 m2 = *reinterpret_cast<const float2*>(mem2 + row + lane * 2);
    const float2 tv = *reinterpret_cast<const float2*>(teacher + b * kD + lane * 2);
    const float2 sv = *reinterpret_cast<const float2*>(student + b * kD + lane * 2);
    float d1 = m1.x * tv.x + m1.y * tv.y;
    float d2 = m2.x * sv.x + m2.y * sv.y;
    #pragma unroll
    for (int off = 32; off > 0; off >>= 1) {
        d1 += __shfl_xor(d1, off);
        d2 += __shfl_xor(d2, off);
    }
    if (lane == 0) {
        e2[wave] = __expf(d1 * kTInv);
        e1[wave] = __expf(d2 * kTInv);
    }
}

__global__ __launch_bounds__(256) void copy_kernel(
    const float* __restrict__ mem1, const float* __restrict__ mem2,
    float* __restrict__ out)
{
    const long long NV4 = (kTot + 1) / 4;
    const long long KS  = kM / 4;
    const float4* m1v = reinterpret_cast<const float4*>(mem1);
    const float4* m2v = reinterpret_cast<const float4*>(mem2);
    float4* ov = reinterpret_cast<float4*>(out);
    long long stride = (long long)gridDim.x * 256;
    for (long long k = (long long)blockIdx.x * 256 + threadIdx.x; k < NV4; k += stride) {
        if (k == 0) {
            out[1] = mem1[0]; out[2] = mem1[1]; out[3] = mem1[2];
            out[kTot] = mem2[kM - 1];
            continue;
        }
        float4 r;
        if (k < KS) {
            float4 a = m1v[k - 1];
            float4 b = m1v[k];
            r = make_float4(a.w, b.x, b.y, b.z);
        } else if (k == KS) {
            r = make_float4(mem1[kM - 1], mem2[0], mem2[1], mem2[2]);
        } else {
            float4 a = m2v[k - KS - 1];
            float4 b = m2v[k - KS];
            r = make_float4(a.w, b.x, b.y, b.z);
        }
        ov[k] = r;
    }
}

// ---------- loss chain ----------

__global__ __launch_bounds__(256) void sums_kernel(
    const float* __restrict__ e2, const float* __restrict__ e1,
    float* __restrict__ p2, float* __restrict__ p1)
{
    __shared__ float s2[256], s1[256];
    float a2 = 0.f, a1 = 0.f;
    for (int i = blockIdx.x * 256 + threadIdx.x; i < kNPair; i += 256 * kRB) {
        a2 += e2[i];
        a1 += e1[i];
    }
    s2[threadIdx.x] = a2; s1[threadIdx.x] = a1;
    __syncthreads();
    for (int st = 128; st > 0; st >>= 1) {
        if ((int)threadIdx.x < st) {
            s2[threadIdx.x] += s2[threadIdx.x + st];
            s1[threadIdx.x] += s1[threadIdx.x + st];
        }
        __syncthreads();
    }
    if (threadIdx.x == 0) { p2[blockIdx.x] = s2[0]; p1[blockIdx.x] = s1[0]; }
}

// z merged in: each block reduces the 256 partials itself (deterministic).
__global__ __launch_bounds__(256) void lossp_kernel(
    const float* __restrict__ e2, const float* __restrict__ e1,
    const float* __restrict__ p2, const float* __restrict__ p1,
    float* __restrict__ lp)
{
    __shared__ float s2[256], s1[256];
    s2[threadIdx.x] = p2[threadIdx.x];
    s1[threadIdx.x] = p1[threadIdx.x];
    __syncthreads();
    for (int st = 128; st > 0; st >>= 1) {
        if ((int)threadIdx.x < st) {
            s2[threadIdx.x] += s2[threadIdx.x + st];
            s1[threadIdx.x] += s1[threadIdx.x + st];
        }
        __syncthreads();
    }
    const float scale = (float)kN / (float)kNPair;
    const float iz2 = 1.0f / (s2[0] * scale);
    const float iz1 = 1.0f / (s1[0] * scale);

    const float mpn = 2048.0f / 500000.0f;
    const float noise = mpn + 1e-7f;
    float acc = 0.f;
    for (int i = blockIdx.x * 256 + threadIdx.x; i < kNPair; i += 256 * kRB) {
        int k = i % kKC;
        float x2 = e2[i] * iz2;
        float x1 = e1[i] * iz1;
        if (k == 0) {
            acc += __logf(x2 / (x2 + noise)) + __logf(x1 / (x1 + noise));
        } else {
            acc += __logf(mpn / (x2 + noise)) + __logf(mpn / (x1 + noise));
        }
    }
    __syncthreads();
    __shared__ float s[256];
    s[threadIdx.x] = acc;
    __syncthreads();
    for (int st = 128; st > 0; st >>= 1) {
        if ((int)threadIdx.x < st) s[threadIdx.x] += s[threadIdx.x + st];
        __syncthreads();
    }
    if (threadIdx.x == 0) lp[blockIdx.x] = s[0];
}

__global__ __launch_bounds__(256) void final_kernel(
    const float* __restrict__ lp, float* __restrict__ out)
{
    __shared__ float s[256];
    s[threadIdx.x] = lp[threadIdx.x];
    __syncthreads();
    for (int st = 128; st > 0; st >>= 1) {
        if ((int)threadIdx.x < st) s[threadIdx.x] += s[threadIdx.x + st];
        __syncthreads();
    }
    if (threadIdx.x == 0) out[0] = -s[0] / (float)kB;
}

// ---------- momentum update of the 256 pos rows ----------

__global__ __launch_bounds__(64) void update_kernel(
    const float* __restrict__ mem1, const float* __restrict__ mem2,
    const float* __restrict__ student, const float* __restrict__ teacher,
    const int* __restrict__ pos_idx,
    float* __restrict__ out1, float* __restrict__ out2)
{
    int b = blockIdx.x;
    int lane = threadIdx.x;
    int p = pos_idx[b];
    for (int b2 = b + 1; b2 < kB; ++b2)
        if (pos_idx[b2] == p) return;   // a later write wins
    long long row = (long long)p * kD;
    float2 m1 = *reinterpret_cast<const float2*>(mem1 + row + lane * 2);
    float2 m2 = *reinterpret_cast<const float2*>(mem2 + row + lane * 2);
    float2 sv = *reinterpret_cast<const float2*>(student + b * kD + lane * 2);
    float2 tv = *reinterpret_cast<const float2*>(teacher + b * kD + lane * 2);
    float2 l1 = make_float2(m1.x * kMom + sv.x * (1.f - kMom),
                            m1.y * kMom + sv.y * (1.f - kMom));
    float2 l2 = make_float2(m2.x * kMom + tv.x * (1.f - kMom),
                            m2.y * kMom + tv.y * (1.f - kMom));
    float n1 = l1.x * l1.x + l1.y * l1.y;
    float n2 = l2.x * l2.x + l2.y * l2.y;
    #pragma unroll
    for (int off = 32; off > 0; off >>= 1) {
        n1 += __shfl_xor(n1, off);
        n2 += __shfl_xor(n2, off);
    }
    float i1 = 1.0f / sqrtf(n1);
    float i2 = 1.0f / sqrtf(n2);
    out1[row + lane * 2]     = l1.x * i1;
    out1[row + lane * 2 + 1] = l1.y * i1;
    out2[row + lane * 2]     = l2.x * i2;
    out2[row + lane * 2 + 1] = l2.y * i2;
}

extern "C" void kernel_launch(void* const* d_in, const int* in_sizes, int n_in,
                              void* d_out, int out_size, void* d_ws, size_t ws_size,
                              hipStream_t stream) {
    const float* student = (const float*)d_in[0];
    const float* teacher = (const float*)d_in[1];
    const float* mem1    = (const float*)d_in[2];
    const float* mem2    = (const float*)d_in[3];
    const int*   pos_idx = (const int*)d_in[4];
    const int*   cidx    = (const int*)d_in[5];

    float* out  = (float*)d_out;
    float* out1 = out + 1;
    float* out2 = out + 1 + kM;

    // ws layout (sorted64 right after e-arrays: 8B-aligned offset)
    float* ws = (float*)d_ws;
    float* e2 = ws;                            // kNPair
    float* e1 = e2 + kNPair;                   // kNPair
    long long* sorted64 = (long long*)(e1 + kNPair);   // kNPair (8B each)
    float* p2 = (float*)(sorted64 + kNPair);   // kRB
    float* p1 = p2 + kRB;                      // kRB
    float* lp = p1 + kRB;                      // kRB
    int*   A    = (int*)(lp + kRB);            // kN counts
    int*   cur  = A + kN;                      // kN scatter cursor
    int*   offs = cur + kN;                    // kN + 1
    int*   bsum = offs + kN + 1;               // kNB1
    int*   bpre = bsum + kNB1;                 // kNB1
    size_t need = (size_t)((char*)(bpre + kNB1) - (char*)d_ws);

    if (ws_size >= need) {
        // CSR setup (A and cur zeroed in one async memset)
        (void)hipMemsetAsync(A, 0, 2 * (size_t)kN * sizeof(int), stream);
        hist_kernel<<<(kNPair + 255) / 256, 256, 0, stream>>>(cidx, A);
        scan1_kernel<<<kNB1, 256, 0, stream>>>(A, bsum);
        scan2_kernel<<<1, 256, 0, stream>>>(bsum, bpre, offs);
        scan3_kernel<<<kNB1, 256, 0, stream>>>(A, bpre, offs);
        scatter_kernel<<<(kNPair + 255) / 256, 256, 0, stream>>>(cidx, offs, cur, sorted64);
        // fused tiled copy + dots, full prefetch pipeline, NT out-stores
        fused9_kernel<<<kGrid9, 256, 0, stream>>>(mem1, mem2, teacher, student,
                                                  offs, sorted64, out, e2, e1);
    } else {
        // fallback: R2 path
        int nblocks = (kNPair + 3) / 4;
        dots_kernel<<<nblocks, 256, 0, stream>>>(mem1, mem2, teacher, student, cidx, e2, e1);
        copy_kernel<<<2048, 256, 0, stream>>>(mem1, mem2, out);
    }

    sums_kernel<<<kRB, 256, 0, stream>>>(e2, e1, p2, p1);
    lossp_kernel<<<kRB, 256, 0, stream>>>(e2, e1, p2, p1, lp);
    final_kernel<<<1, 256, 0, stream>>>(lp, out);
    update_kernel<<<kB, 64, 0, stream>>>(mem1, mem2, student, teacher, pos_idx, out1, out2);
}